// Round 1
// baseline (292.848 us; speedup 1.0000x reference)
//
#include <hip/hip_runtime.h>
#include <math.h>

#define NH 32
#define NKV 8
#define HD 128
#define HDIM 4096
#define KVDIM 1024
#define TPREV 16383
#define NCHUNK 128
#define CHUNK 128

// ws layout (floats)
#define OFF_Q 0
#define OFF_K 4096
#define OFF_V 5120
#define OFF_PART 6144
#define PART_STRIDE 130
#define OFF_CTX (OFF_PART + NH * NCHUNK * PART_STRIDE)  // 538624, 16B-aligned

__device__ __forceinline__ float wave_reduce_sum(float v) {
#pragma unroll
  for (int m = 32; m >= 1; m >>= 1) v += __shfl_xor(v, m, 64);
  return v;
}
__device__ __forceinline__ float wave_reduce_max(float v) {
#pragma unroll
  for (int m = 32; m >= 1; m >>= 1) v = fmaxf(v, __shfl_xor(v, m, 64));
  return v;
}
__device__ __forceinline__ float dot4(float4 a, float4 b) {
  return a.x * b.x + a.y * b.y + a.z * b.z + a.w * b.w;
}

// ---------------------------------------------------------------------------
// Kernel 1: fused QKV matvec + RoPE. One row per 64-lane wave, 4 rows/block.
// 8-deep load batches force MLP (8 KB W-bytes in flight per wave).
// RoPE epilogue: 10^(-j/16) via exact fp64 binary-product table (4 muls),
// fp64 mod-2pi reduction, then fast fp32 sincos — no software-fp64
// pow/cos/sin on the block tail. Angle error ~2e-12 rad (was the reason
// for fp64: fp32 angle at pos=16383 has ~1e-3 rad error -> breach tol).
// ---------------------------------------------------------------------------
__global__ __launch_bounds__(256) void qkv_rope_kernel(
    const float* __restrict__ Wq, const float* __restrict__ Wk,
    const float* __restrict__ Wv, const float* __restrict__ hidden,
    const int* __restrict__ pos_p, float* __restrict__ ws) {
  int r = blockIdx.x * 4 + (threadIdx.x >> 6);
  int lane = threadIdx.x & 63;
  const float* W;
  int wr;
  if (r < HDIM) {
    W = Wq; wr = r;
  } else if (r < HDIM + KVDIM) {
    W = Wk; wr = r - HDIM;
  } else {
    W = Wv; wr = r - HDIM - KVDIM;
  }
  const float4* w4 = (const float4*)(W + (size_t)wr * HDIM);
  const float4* h4 = (const float4*)hidden;
  float s = 0.f;
#pragma unroll
  for (int base = 0; base < 16; base += 8) {
    float4 a[8], b[8];
#pragma unroll
    for (int j = 0; j < 8; ++j) a[j] = w4[lane + 64 * (base + j)];
#pragma unroll
    for (int j = 0; j < 8; ++j) b[j] = h4[lane + 64 * (base + j)];
#pragma unroll
    for (int j = 0; j < 8; ++j) s += dot4(a[j], b[j]);
  }
  s = wave_reduce_sum(s);
  __shared__ float rs[4];
  if (lane == 0) rs[threadIdx.x >> 6] = s;
  __syncthreads();
  if (threadIdx.x < 2) {
    int r0 = blockIdx.x * 4 + (int)threadIdx.x * 2;
    float S0 = rs[threadIdx.x * 2], S1 = rs[threadIdx.x * 2 + 1];
    if (r0 < HDIM + KVDIM) {
      int j = (r0 & (HD - 1)) >> 1;  // 0..63
      // inv_freq = 10^(-j/16), exact binary decomposition in fp64.
      // Constants verified: a1^2 == a2, a2^2 == a4, a4^2 == a8^... chain.
      double lowp = 1.0;
      if (j & 1) lowp *= 0.8659643233600653;   // 10^(-1/16)
      if (j & 2) lowp *= 0.7498942093324559;   // 10^(-1/8)
      if (j & 4) lowp *= 0.5623413251903491;   // 10^(-1/4)
      if (j & 8) lowp *= 0.31622776601683794;  // 10^(-1/2)
      double hi = (j & 16) ? 0.1 : 1.0;
      if (j & 32) hi *= 0.01;
      double f = (double)(*pos_p) * (lowp * hi);
      // reduce mod 2*pi in fp64 (hardware mul/fma/floor; no libm fp64)
      double k2 = floor(f * 0.15915494309189535);
      double rr = f - k2 * 6.283185307179586;
      float fr = (float)rr;
      float c = cosf(fr), sn = sinf(fr);
      ws[r0] = S0 * c - S1 * sn;
      ws[r0 + 1] = S0 * sn + S1 * c;
    } else {
      ws[r0] = S0;
      ws[r0 + 1] = S1;
    }
  }
}

// ---------------------------------------------------------------------------
// Kernel 2: flash-decoding chunks. Block = (kv head g, 128-token chunk c).
// Grid 1024 = 4 blocks/CU (VGPR-128 residency limit; was 512 = 2/CU and
// latency-bound at Occupancy 16% / VALUBusy 7% / HBM 15%).
// Phase A: 2 LANES PER TOKEN — each lane streams 64 of the token's 128
//          K-dims (256B) in 8-deep float4 batches; one shfl_xor combines.
// Phase B: 8 token-groups x 32 lanes, 4-deep batched float4 V loads.
// ---------------------------------------------------------------------------
__global__ __launch_bounds__(256, 4) void attn_chunk_kernel(
    const float* __restrict__ k_cache, const float* __restrict__ v_cache,
    float* __restrict__ ws) {
  int g = blockIdx.x >> 7;  // NCHUNK = 128
  int c = blockIdx.x & 127;
  int t0 = c * CHUNK;
  int tid = threadIdx.x;

  __shared__ float qs[4 * HD];       // 2 KB
  __shared__ float sc[CHUNK * 5];    // 2.5 KB, stride 5 -> conflict-free
  __shared__ float vacc[8][4][HD];   // 16 KB
  __shared__ float wredm[4][4], wredl[4][4];
  __shared__ float mh[4], lh[4];

  for (int i = tid; i < 4 * HD; i += 256) qs[i] = ws[OFF_Q + g * 4 * HD + i];
  __syncthreads();

  const float rscale = 0.08838834764831845f;  // 1/sqrt(128)

  // --- Phase A: scores, two lanes per token (lane pair = dim halves) ---
  int itok = tid >> 1;  // token index within chunk, 0..127
  int hf = tid & 1;     // which 64-dim half
  int tok = t0 + itok;
  bool valid = tok < TPREV;
  float s0 = -1e30f, s1 = -1e30f, s2 = -1e30f, s3 = -1e30f;
  if (valid) {
    const float4* kp =
        (const float4*)(k_cache + (size_t)tok * KVDIM + g * HD + hf * 64);
    const float4* q4 = (const float4*)qs;  // head h at index h*32 + i
    s0 = 0.f; s1 = 0.f; s2 = 0.f; s3 = 0.f;
#pragma unroll
    for (int base = 0; base < 16; base += 8) {
      float4 kk[8];
#pragma unroll
      for (int j = 0; j < 8; ++j) kk[j] = kp[base + j];
#pragma unroll
      for (int j = 0; j < 8; ++j) {
        int qi = hf * 16 + base + j;
        s0 += dot4(kk[j], q4[0 * 32 + qi]);
        s1 += dot4(kk[j], q4[1 * 32 + qi]);
        s2 += dot4(kk[j], q4[2 * 32 + qi]);
        s3 += dot4(kk[j], q4[3 * 32 + qi]);
      }
    }
  }
  // combine the two dim-halves: lane pair (2i, 2i+1) both end with full score
  s0 += __shfl_xor(s0, 1, 64);
  s1 += __shfl_xor(s1, 1, 64);
  s2 += __shfl_xor(s2, 1, 64);
  s3 += __shfl_xor(s3, 1, 64);
  s0 *= rscale; s1 *= rscale; s2 *= rscale; s3 *= rscale;

  // --- block max per head (token duplication is harmless for max) ---
  float m0 = wave_reduce_max(s0), m1 = wave_reduce_max(s1);
  float m2 = wave_reduce_max(s2), m3 = wave_reduce_max(s3);
  if ((tid & 63) == 0) {
    int w = tid >> 6;
    wredm[w][0] = m0; wredm[w][1] = m1; wredm[w][2] = m2; wredm[w][3] = m3;
  }
  __syncthreads();
  if (tid < 4)
    mh[tid] = fmaxf(fmaxf(wredm[0][tid], wredm[1][tid]),
                    fmaxf(wredm[2][tid], wredm[3][tid]));
  __syncthreads();

  // --- exp + sum (masked tokens: s very negative -> e=0; each token is
  //     counted twice in the wave sum -> *0.5) ---
  float e0 = expf(s0 - mh[0]), e1 = expf(s1 - mh[1]);
  float e2 = expf(s2 - mh[2]), e3 = expf(s3 - mh[3]);
  if (hf == 0) {
    sc[itok * 5 + 0] = e0;
    sc[itok * 5 + 1] = e1;
    sc[itok * 5 + 2] = e2;
    sc[itok * 5 + 3] = e3;
  }
  float l0 = 0.5f * wave_reduce_sum(e0), l1 = 0.5f * wave_reduce_sum(e1);
  float l2 = 0.5f * wave_reduce_sum(e2), l3 = 0.5f * wave_reduce_sum(e3);
  if ((tid & 63) == 0) {
    int w = tid >> 6;
    wredl[w][0] = l0; wredl[w][1] = l1; wredl[w][2] = l2; wredl[w][3] = l3;
  }
  __syncthreads();
  if (tid < 4)
    lh[tid] = wredl[0][tid] + wredl[1][tid] + wredl[2][tid] + wredl[3][tid];
  __syncthreads();

  // --- Phase B: V accumulation, 4-deep batched float4 loads ---
  int grp = tid >> 5, lane = tid & 31;
  float4 a0 = {0, 0, 0, 0}, a1 = {0, 0, 0, 0}, a2 = {0, 0, 0, 0},
         a3 = {0, 0, 0, 0};
  const float4 z4 = {0, 0, 0, 0};
#pragma unroll
  for (int base = 0; base < 16; base += 4) {
    float4 vv[4];
#pragma unroll
    for (int j = 0; j < 4; ++j) {
      int it = grp + 8 * (base + j);
      int t = t0 + it;
      vv[j] = (t < TPREV)
                  ? ((const float4*)(v_cache + (size_t)t * KVDIM + g * HD))[lane]
                  : z4;
    }
#pragma unroll
    for (int j = 0; j < 4; ++j) {
      int it = grp + 8 * (base + j);
      float p0 = sc[it * 5 + 0], p1 = sc[it * 5 + 1];
      float p2 = sc[it * 5 + 2], p3 = sc[it * 5 + 3];
      a0.x = fmaf(p0, vv[j].x, a0.x); a0.y = fmaf(p0, vv[j].y, a0.y);
      a0.z = fmaf(p0, vv[j].z, a0.z); a0.w = fmaf(p0, vv[j].w, a0.w);
      a1.x = fmaf(p1, vv[j].x, a1.x); a1.y = fmaf(p1, vv[j].y, a1.y);
      a1.z = fmaf(p1, vv[j].z, a1.z); a1.w = fmaf(p1, vv[j].w, a1.w);
      a2.x = fmaf(p2, vv[j].x, a2.x); a2.y = fmaf(p2, vv[j].y, a2.y);
      a2.z = fmaf(p2, vv[j].z, a2.z); a2.w = fmaf(p2, vv[j].w, a2.w);
      a3.x = fmaf(p3, vv[j].x, a3.x); a3.y = fmaf(p3, vv[j].y, a3.y);
      a3.z = fmaf(p3, vv[j].z, a3.z); a3.w = fmaf(p3, vv[j].w, a3.w);
    }
  }
  ((float4*)&vacc[grp][0][0])[lane] = a0;
  ((float4*)&vacc[grp][1][0])[lane] = a1;
  ((float4*)&vacc[grp][2][0])[lane] = a2;
  ((float4*)&vacc[grp][3][0])[lane] = a3;
  __syncthreads();

  // --- cross-group reduce + global write of partials ---
  float* part = ws + OFF_PART;
#pragma unroll
  for (int rep = 0; rep < 2; ++rep) {
    int p = tid + rep * 256;  // p in [0,512): h = p>>7, d = p&127
    int h = p >> 7, d = p & 127;
    float s = 0.f;
#pragma unroll
    for (int g2 = 0; g2 < 8; ++g2) s += vacc[g2][h][d];
    part[(size_t)((g * 4 + h) * NCHUNK + c) * PART_STRIDE + d] = s;
  }
  if (tid < 4) {
    part[(size_t)((g * 4 + tid) * NCHUNK + c) * PART_STRIDE + 128] = mh[tid];
    part[(size_t)((g * 4 + tid) * NCHUNK + c) * PART_STRIDE + 129] = lh[tid];
  }
}

// ---------------------------------------------------------------------------
// Kernel 3: combine 128 partials + new token per q head. 256 threads.
// ---------------------------------------------------------------------------
__global__ __launch_bounds__(256) void combine_kernel(float* __restrict__ ws) {
  int h = blockIdx.x;
  int g = h >> 2;
  int tid = threadIdx.x;
  const float rscale = 0.08838834764831845f;
  const float* ph = ws + OFF_PART + (size_t)h * NCHUNK * PART_STRIDE;

  __shared__ float red[HD];
  __shared__ float wexp[NCHUNK];
  __shared__ float wm[4], wl[4];
  __shared__ float acc2[HD];

  // dot(q_h, k_new)
  if (tid < HD) red[tid] = ws[OFF_Q + h * HD + tid] * ws[OFF_K + g * HD + tid];
  __syncthreads();
#pragma unroll
  for (int s2 = 64; s2 >= 1; s2 >>= 1) {
    if (tid < s2 && tid + s2 < HD) red[tid] += red[tid + s2];
    __syncthreads();
  }
  float snew = red[0] * rscale;

  // chunk (m,l) pairs: first 128 threads, block-reduce across 4 waves
  float mv = (tid < NCHUNK) ? ph[(size_t)tid * PART_STRIDE + 128] : -1e30f;
  float lv = (tid < NCHUNK) ? ph[(size_t)tid * PART_STRIDE + 129] : 0.f;
  float mw = wave_reduce_max(mv);
  if ((tid & 63) == 0) wm[tid >> 6] = mw;
  __syncthreads();
  float M = fmaxf(fmaxf(fmaxf(wm[0], wm[1]), fmaxf(wm[2], wm[3])), snew);
  float w = expf(mv - M);  // tid >= NCHUNK: exp(very negative) = 0
  if (tid < NCHUNK) wexp[tid] = w;
  float lw = wave_reduce_sum(lv * w);
  if ((tid & 63) == 0) wl[tid >> 6] = lw;
  __syncthreads();
  float en = expf(snew - M);
  float L = wl[0] + wl[1] + wl[2] + wl[3] + en;

  // accumulate: 2 chunk-halves x 128 dims, 64 iters each
  int half = tid >> 7, d = tid & 127;
  float acc = 0.f;
  int cbeg = half * (NCHUNK / 2);
#pragma unroll 8
  for (int c2 = cbeg; c2 < cbeg + NCHUNK / 2; ++c2)
    acc = fmaf(ph[(size_t)c2 * PART_STRIDE + d], wexp[c2], acc);
  if (half == 0) acc2[d] = acc;
  __syncthreads();
  if (half == 1) acc2[d] += acc;
  __syncthreads();
  if (tid < HD)
    ws[OFF_CTX + h * HD + tid] =
        (acc2[tid] + en * ws[OFF_V + g * HD + tid]) / L;
}

// ---------------------------------------------------------------------------
// Kernel 4: out = Wo @ ctx. One row per wave, batched loads, no barriers.
// ---------------------------------------------------------------------------
__global__ __launch_bounds__(256) void out_matvec_kernel(
    const float* __restrict__ Wo, const float* __restrict__ ws,
    float* __restrict__ out) {
  int r = blockIdx.x * 4 + (threadIdx.x >> 6);
  int lane = threadIdx.x & 63;
  const float4* w4 = (const float4*)(Wo + (size_t)r * HDIM);
  const float4* x4 = (const float4*)(ws + OFF_CTX);
  float s = 0.f;
#pragma unroll
  for (int base = 0; base < 16; base += 8) {
    float4 a[8], b[8];
#pragma unroll
    for (int j = 0; j < 8; ++j) a[j] = w4[lane + 64 * (base + j)];
#pragma unroll
    for (int j = 0; j < 8; ++j) b[j] = x4[lane + 64 * (base + j)];
#pragma unroll
    for (int j = 0; j < 8; ++j) s += dot4(a[j], b[j]);
  }
  s = wave_reduce_sum(s);
  if (lane == 0) out[r] = s;
}

extern "C" void kernel_launch(void* const* d_in, const int* in_sizes, int n_in,
                              void* d_out, int out_size, void* d_ws,
                              size_t ws_size, hipStream_t stream) {
  const float* hidden = (const float*)d_in[0];
  const float* k_cache = (const float*)d_in[1];
  const float* v_cache = (const float*)d_in[2];
  const float* Wq = (const float*)d_in[3];
  const float* Wk = (const float*)d_in[4];
  const float* Wv = (const float*)d_in[5];
  const float* Wo = (const float*)d_in[6];
  const int* pos = (const int*)d_in[7];
  float* out = (float*)d_out;
  float* ws = (float*)d_ws;

  qkv_rope_kernel<<<(HDIM + 2 * KVDIM) / 4, 256, 0, stream>>>(Wq, Wk, Wv,
                                                              hidden, pos, ws);
  attn_chunk_kernel<<<NKV * NCHUNK, 256, 0, stream>>>(k_cache, v_cache, ws);
  combine_kernel<<<NH, 256, 0, stream>>>(ws);
  out_matvec_kernel<<<HDIM / 4, 256, 0, stream>>>(Wo, ws, out);
}

// Round 3
// 287.124 us; speedup vs baseline: 1.0199x; 1.0199x over previous
//
#include <hip/hip_runtime.h>
#include <math.h>
#include <stdint.h>

#define NH 32
#define NKV 8
#define HD 128
#define HDIM 4096
#define KVDIM 1024
#define TPREV 16383
#define NCHUNK 128
#define CHUNK 128  // tokens per block = 2 passes x 64
#define PTOK 64    // tokens per pass

// ws layout (floats)
#define OFF_Q 0
#define OFF_K 4096
#define OFF_V 5120
#define OFF_PART 6144
#define PART_STRIDE 132  // 528B, 16B-aligned for float4 partial writes
#define OFF_CTX (OFF_PART + NH * NCHUNK * PART_STRIDE)  // 546816

__device__ __forceinline__ float wave_reduce_sum(float v) {
#pragma unroll
  for (int m = 32; m >= 1; m >>= 1) v += __shfl_xor(v, m, 64);
  return v;
}
__device__ __forceinline__ float wave_reduce_max(float v) {
#pragma unroll
  for (int m = 32; m >= 1; m >>= 1) v = fmaxf(v, __shfl_xor(v, m, 64));
  return v;
}
__device__ __forceinline__ float dot4(float4 a, float4 b) {
  return a.x * b.x + a.y * b.y + a.z * b.z + a.w * b.w;
}

// async global->LDS; LDS dst is WAVE-UNIFORM base + lane*16 (linear)
typedef const __attribute__((address_space(1))) unsigned int* gld_gp;
typedef __attribute__((address_space(3))) unsigned int* gld_lp;
__device__ __forceinline__ void cp16(const float* g, float* l) {
  __builtin_amdgcn_global_load_lds((gld_gp)(uintptr_t)g,
                                   (gld_lp)(uint32_t)(uintptr_t)l, 16, 0, 0);
}

#define BAR_LGKM()                                       \
  do {                                                   \
    asm volatile("s_waitcnt lgkmcnt(0)" ::: "memory");   \
    __builtin_amdgcn_s_barrier();                        \
    asm volatile("" ::: "memory");                       \
  } while (0)

// ---------------------------------------------------------------------------
// Kernel 1: fused QKV matvec + RoPE (unchanged).
// ---------------------------------------------------------------------------
__global__ __launch_bounds__(256) void qkv_rope_kernel(
    const float* __restrict__ Wq, const float* __restrict__ Wk,
    const float* __restrict__ Wv, const float* __restrict__ hidden,
    const int* __restrict__ pos_p, float* __restrict__ ws) {
  int r = blockIdx.x * 4 + (threadIdx.x >> 6);
  int lane = threadIdx.x & 63;
  const float* W;
  int wr;
  if (r < HDIM) {
    W = Wq; wr = r;
  } else if (r < HDIM + KVDIM) {
    W = Wk; wr = r - HDIM;
  } else {
    W = Wv; wr = r - HDIM - KVDIM;
  }
  const float4* w4 = (const float4*)(W + (size_t)wr * HDIM);
  const float4* h4 = (const float4*)hidden;
  float s = 0.f;
#pragma unroll
  for (int base = 0; base < 16; base += 8) {
    float4 a[8], b[8];
#pragma unroll
    for (int j = 0; j < 8; ++j) a[j] = w4[lane + 64 * (base + j)];
#pragma unroll
    for (int j = 0; j < 8; ++j) b[j] = h4[lane + 64 * (base + j)];
#pragma unroll
    for (int j = 0; j < 8; ++j) s += dot4(a[j], b[j]);
  }
  s = wave_reduce_sum(s);
  __shared__ float rs[4];
  if (lane == 0) rs[threadIdx.x >> 6] = s;
  __syncthreads();
  if (threadIdx.x < 2) {
    int r0 = blockIdx.x * 4 + (int)threadIdx.x * 2;
    float S0 = rs[threadIdx.x * 2], S1 = rs[threadIdx.x * 2 + 1];
    if (r0 < HDIM + KVDIM) {
      int j = (r0 & (HD - 1)) >> 1;  // 0..63
      double lowp = 1.0;
      if (j & 1) lowp *= 0.8659643233600653;   // 10^(-1/16)
      if (j & 2) lowp *= 0.7498942093324559;   // 10^(-1/8)
      if (j & 4) lowp *= 0.5623413251903491;   // 10^(-1/4)
      if (j & 8) lowp *= 0.31622776601683794;  // 10^(-1/2)
      double hi = (j & 16) ? 0.1 : 1.0;
      if (j & 32) hi *= 0.01;
      double f = (double)(*pos_p) * (lowp * hi);
      double k2 = floor(f * 0.15915494309189535);
      double rr = f - k2 * 6.283185307179586;
      float fr = (float)rr;
      float c = cosf(fr), sn = sinf(fr);
      ws[r0] = S0 * c - S1 * sn;
      ws[r0 + 1] = S0 * sn + S1 * c;
    } else {
      ws[r0] = S0;
      ws[r0 + 1] = S1;
    }
  }
}

// ---------------------------------------------------------------------------
// Kernel 2: flash-decoding, async-LDS pipelined. Block = (g, 128-tok chunk).
// 2 passes of 64 tokens; counted vmcnt + raw s_barrier (loads stay in flight
// across barriers; never drain to 0 in the loop).
// Lane map: tokl = w*16 + (l&15), qq = l>>4 -> each 16-lane phase is 16
// DISTINCT tokens; with the ^(t&7) src-side slot swizzle (rule 21: linear
// gl_lds dst, pre-swizzled global src) K ds_read_b128 is 2-per-bank-group
// (free). q reads are phase-uniform broadcasts (linear q layout).
// ---------------------------------------------------------------------------
__global__ __launch_bounds__(256, 2) void attn_chunk_kernel(
    const float* __restrict__ k_cache, const float* __restrict__ v_cache,
    float* __restrict__ ws) {
  int g = blockIdx.x >> 7;  // NCHUNK = 128
  int c = blockIdx.x & 127;
  int t0 = c * CHUNK;
  int tid = threadIdx.x;
  int l = tid & 63, w = tid >> 6;

  __shared__ __align__(16) float Klds[PTOK * HD];  // 32KB, swizzled; vacc later
  __shared__ __align__(16) float Vlds[PTOK * HD];  // 32KB, linear [tok][d]
  __shared__ __align__(16) float qs[4 * HD];       // 2KB, LINEAR
  __shared__ float sc[PTOK * 5];                   // 1.25KB
  __shared__ float rm[4], rl[4], wold[4];
  __shared__ float wredm[4][4], wredl[4][4];

  if (tid < 4) { rm[tid] = -1e30f; rl[tid] = 0.f; }

  // ---- stage q linearly: waves 0,1 each 1KB via one cp16 ----
  if (w < 2)
    cp16(ws + OFF_Q + (g << 9) + (w << 8) + (l << 2), qs + (w << 8));
  // ---- stage K pass 0 (8 cp16/wave, XOR-swizzled global source) ----
#pragma unroll
  for (int i = 0; i < 8; ++i) {
    int tokA = (w << 4) + 2 * i;
    int toks = tokA + (l >> 5);
    int gt = t0 + toks;
    if (gt >= TPREV) gt = 0;
    cp16(k_cache + (size_t)gt * KVDIM + g * HD + (((l & 31) ^ (toks & 7)) << 2),
         Klds + (tokA << 7));
  }
  // ---- stage V pass 0 (linear) ----
#pragma unroll
  for (int i = 0; i < 8; ++i) {
    int tokA = (w << 4) + 2 * i;
    int toks = tokA + (l >> 5);
    int gt = t0 + toks;
    if (gt >= TPREV) gt = 0;
    cp16(v_cache + (size_t)gt * KVDIM + g * HD + ((l & 31) << 2),
         Vlds + (tokA << 7));
  }
  // own q + K0 landed (V0 = 8 newest outstanding); barrier -> all visible
  asm volatile("s_waitcnt vmcnt(8) lgkmcnt(0)" ::: "memory");
  __builtin_amdgcn_s_barrier();
  asm volatile("" ::: "memory");

  const float rscale = 0.08838834764831845f;  // 1/sqrt(128)
  int tokl = (w << 4) + (l & 15);  // pass-local token (16 distinct per phase)
  int qq = l >> 4;                 // 32-dim quarter
  int t7 = tokl & 7;
  int grp8 = tid >> 5, d4 = tid & 31;  // PV mapping
  float4 acc0 = {0, 0, 0, 0}, acc1 = {0, 0, 0, 0};
  float4 acc2 = {0, 0, 0, 0}, acc3 = {0, 0, 0, 0};
  const float4* K4 = (const float4*)Klds;
  const float4* q4 = (const float4*)qs;
  const float4* V4 = (const float4*)Vlds;

#pragma unroll
  for (int p = 0; p < 2; ++p) {
    // --- QK: 4 heads over this thread's 32-dim quarter ---
    float s0 = 0.f, s1 = 0.f, s2 = 0.f, s3 = 0.f;
#pragma unroll
    for (int j = 0; j < 8; ++j) {
      float4 kk = K4[(tokl << 5) + (qq << 3) + (j ^ t7)];
      float4 qa = q4[0 * 32 + (qq << 3) + j];
      float4 qb = q4[1 * 32 + (qq << 3) + j];
      float4 qc = q4[2 * 32 + (qq << 3) + j];
      float4 qd_ = q4[3 * 32 + (qq << 3) + j];
      s0 += dot4(kk, qa); s1 += dot4(kk, qb);
      s2 += dot4(kk, qc); s3 += dot4(kk, qd_);
    }
    // combine the 4 quarters (token's quarters at lanes (l&15)+16*qq)
    s0 += __shfl_xor(s0, 16, 64); s0 += __shfl_xor(s0, 32, 64);
    s1 += __shfl_xor(s1, 16, 64); s1 += __shfl_xor(s1, 32, 64);
    s2 += __shfl_xor(s2, 16, 64); s2 += __shfl_xor(s2, 32, 64);
    s3 += __shfl_xor(s3, 16, 64); s3 += __shfl_xor(s3, 32, 64);
    s0 *= rscale; s1 *= rscale; s2 *= rscale; s3 *= rscale;
    if (t0 + p * PTOK + tokl >= TPREV) {
      s0 = -1e30f; s1 = -1e30f; s2 = -1e30f; s3 = -1e30f;
    }

    // --- block max per head ---
    float m0 = wave_reduce_max(s0), m1 = wave_reduce_max(s1);
    float m2 = wave_reduce_max(s2), m3 = wave_reduce_max(s3);
    if (l == 0) {
      wredm[w][0] = m0; wredm[w][1] = m1; wredm[w][2] = m2; wredm[w][3] = m3;
    }
    BAR_LGKM();  // (A) — everyone done reading K_p
    if (p == 0) {  // stage K pass 1 into freed K LDS
#pragma unroll
      for (int i = 0; i < 8; ++i) {
        int tokA = (w << 4) + 2 * i;
        int toks = tokA + (l >> 5);
        int gt = t0 + PTOK + toks;
        if (gt >= TPREV) gt = 0;
        cp16(k_cache + (size_t)gt * KVDIM + g * HD +
                 (((l & 31) ^ (toks & 7)) << 2),
             Klds + (tokA << 7));
      }
    }
    if (tid < 4) {
      float mh = fmaxf(fmaxf(wredm[0][tid], wredm[1][tid]),
                       fmaxf(wredm[2][tid], wredm[3][tid]));
      float M = fmaxf(rm[tid], mh);
      wold[tid] = expf(rm[tid] - M);
      rm[tid] = M;
    }
    BAR_LGKM();  // (B)

    float M0 = rm[0], M1 = rm[1], M2 = rm[2], M3 = rm[3];
    float w0 = wold[0], w1 = wold[1], w2 = wold[2], w3 = wold[3];
    acc0.x *= w0; acc0.y *= w0; acc0.z *= w0; acc0.w *= w0;
    acc1.x *= w1; acc1.y *= w1; acc1.z *= w1; acc1.w *= w1;
    acc2.x *= w2; acc2.y *= w2; acc2.z *= w2; acc2.w *= w2;
    acc3.x *= w3; acc3.y *= w3; acc3.z *= w3; acc3.w *= w3;

    float e0 = expf(s0 - M0), e1 = expf(s1 - M1);
    float e2 = expf(s2 - M2), e3 = expf(s3 - M3);
    if (qq == 0) {  // lanes 0..15: one writer per token
      sc[tokl * 5 + 0] = e0; sc[tokl * 5 + 1] = e1;
      sc[tokl * 5 + 2] = e2; sc[tokl * 5 + 3] = e3;
    }
    float l0 = 0.25f * wave_reduce_sum(e0), l1 = 0.25f * wave_reduce_sum(e1);
    float l2 = 0.25f * wave_reduce_sum(e2), l3 = 0.25f * wave_reduce_sum(e3);
    if (l == 0) {
      wredl[w][0] = l0; wredl[w][1] = l1; wredl[w][2] = l2; wredl[w][3] = l3;
    }
    // (C): own V_p landed (p0: K1 = 8 newest stay in flight; p1: drain)
    if (p == 0)
      asm volatile("s_waitcnt vmcnt(8) lgkmcnt(0)" ::: "memory");
    else
      asm volatile("s_waitcnt vmcnt(0) lgkmcnt(0)" ::: "memory");
    __builtin_amdgcn_s_barrier();
    asm volatile("" ::: "memory");
    if (tid < 4)
      rl[tid] = rl[tid] * wold[tid] + wredl[0][tid] + wredl[1][tid] +
                wredl[2][tid] + wredl[3][tid];

    // --- PV: 8 tokens per 32-lane group (contiguous b128 = conflict-free) ---
#pragma unroll
    for (int t = 0; t < 8; ++t) {
      int tok = (grp8 << 3) + t;
      float4 vv = V4[(tok << 5) + d4];
      float p0_ = sc[tok * 5 + 0], p1_ = sc[tok * 5 + 1];
      float p2_ = sc[tok * 5 + 2], p3_ = sc[tok * 5 + 3];
      acc0.x = fmaf(p0_, vv.x, acc0.x); acc0.y = fmaf(p0_, vv.y, acc0.y);
      acc0.z = fmaf(p0_, vv.z, acc0.z); acc0.w = fmaf(p0_, vv.w, acc0.w);
      acc1.x = fmaf(p1_, vv.x, acc1.x); acc1.y = fmaf(p1_, vv.y, acc1.y);
      acc1.z = fmaf(p1_, vv.z, acc1.z); acc1.w = fmaf(p1_, vv.w, acc1.w);
      acc2.x = fmaf(p2_, vv.x, acc2.x); acc2.y = fmaf(p2_, vv.y, acc2.y);
      acc2.z = fmaf(p2_, vv.z, acc2.z); acc2.w = fmaf(p2_, vv.w, acc2.w);
      acc3.x = fmaf(p3_, vv.x, acc3.x); acc3.y = fmaf(p3_, vv.y, acc3.y);
      acc3.z = fmaf(p3_, vv.z, acc3.z); acc3.w = fmaf(p3_, vv.w, acc3.w);
    }

    if (p == 0) {
      BAR_LGKM();  // (D) all done reading V0 + sc
      // stage V pass 1
#pragma unroll
      for (int i = 0; i < 8; ++i) {
        int tokA = (w << 4) + 2 * i;
        int toks = tokA + (l >> 5);
        int gt = t0 + PTOK + toks;
        if (gt >= TPREV) gt = 0;
        cp16(v_cache + (size_t)gt * KVDIM + g * HD + ((l & 31) << 2),
             Vlds + (tokA << 7));
      }
      // own K1 landed (V1 = 8 newest); K reads are wave-local -> no barrier
      asm volatile("s_waitcnt vmcnt(8)" ::: "memory");
    }
  }

  // --- cross-group reduce (vacc aliases Klds) + partial write ---
  float4* vacc4 = (float4*)Klds;
  vacc4[(grp8 * 4 + 0) * 32 + d4] = acc0;
  vacc4[(grp8 * 4 + 1) * 32 + d4] = acc1;
  vacc4[(grp8 * 4 + 2) * 32 + d4] = acc2;
  vacc4[(grp8 * 4 + 3) * 32 + d4] = acc3;
  BAR_LGKM();
  if (tid < 128) {
    int h = tid >> 5, dd = tid & 31;
    float4 s = {0, 0, 0, 0};
#pragma unroll
    for (int g2 = 0; g2 < 8; ++g2) {
      float4 v = vacc4[(g2 * 4 + h) * 32 + dd];
      s.x += v.x; s.y += v.y; s.z += v.z; s.w += v.w;
    }
    float* dst = ws + OFF_PART +
                 ((size_t)(g * 4 + h) * NCHUNK + c) * PART_STRIDE + (dd << 2);
    *(float4*)dst = s;
  }
  if (tid < 4) {
    float* base =
        ws + OFF_PART + ((size_t)(g * 4 + tid) * NCHUNK + c) * PART_STRIDE;
    base[128] = rm[tid];
    base[129] = rl[tid];
  }
}

// ---------------------------------------------------------------------------
// Kernel 3: combine 128 partials + new token per q head. 256 threads.
// ---------------------------------------------------------------------------
__global__ __launch_bounds__(256) void combine_kernel(float* __restrict__ ws) {
  int h = blockIdx.x;
  int g = h >> 2;
  int tid = threadIdx.x;
  const float rscale = 0.08838834764831845f;
  const float* ph = ws + OFF_PART + (size_t)h * NCHUNK * PART_STRIDE;

  __shared__ float red[HD];
  __shared__ float wexp[NCHUNK];
  __shared__ float wm[4], wl[4];
  __shared__ float acc2[HD];

  // dot(q_h, k_new)
  if (tid < HD) red[tid] = ws[OFF_Q + h * HD + tid] * ws[OFF_K + g * HD + tid];
  __syncthreads();
#pragma unroll
  for (int s2 = 64; s2 >= 1; s2 >>= 1) {
    if (tid < s2 && tid + s2 < HD) red[tid] += red[tid + s2];
    __syncthreads();
  }
  float snew = red[0] * rscale;

  float mv = (tid < NCHUNK) ? ph[(size_t)tid * PART_STRIDE + 128] : -1e30f;
  float lv = (tid < NCHUNK) ? ph[(size_t)tid * PART_STRIDE + 129] : 0.f;
  float mw = wave_reduce_max(mv);
  if ((tid & 63) == 0) wm[tid >> 6] = mw;
  __syncthreads();
  float M = fmaxf(fmaxf(fmaxf(wm[0], wm[1]), fmaxf(wm[2], wm[3])), snew);
  float w = expf(mv - M);
  if (tid < NCHUNK) wexp[tid] = w;
  float lw = wave_reduce_sum(lv * w);
  if ((tid & 63) == 0) wl[tid >> 6] = lw;
  __syncthreads();
  float en = expf(snew - M);
  float L = wl[0] + wl[1] + wl[2] + wl[3] + en;

  int half = tid >> 7, d = tid & 127;
  float acc = 0.f;
  int cbeg = half * (NCHUNK / 2);
#pragma unroll 8
  for (int c2 = cbeg; c2 < cbeg + NCHUNK / 2; ++c2)
    acc = fmaf(ph[(size_t)c2 * PART_STRIDE + d], wexp[c2], acc);
  if (half == 0) acc2[d] = acc;
  __syncthreads();
  if (half == 1) acc2[d] += acc;
  __syncthreads();
  if (tid < HD)
    ws[OFF_CTX + h * HD + tid] =
        (acc2[tid] + en * ws[OFF_V + g * HD + tid]) / L;
}

// ---------------------------------------------------------------------------
// Kernel 4: out = Wo @ ctx. One row per wave, batched loads, no barriers.
// ---------------------------------------------------------------------------
__global__ __launch_bounds__(256) void out_matvec_kernel(
    const float* __restrict__ Wo, const float* __restrict__ ws,
    float* __restrict__ out) {
  int r = blockIdx.x * 4 + (threadIdx.x >> 6);
  int lane = threadIdx.x & 63;
  const float4* w4 = (const float4*)(Wo + (size_t)r * HDIM);
  const float4* x4 = (const float4*)(ws + OFF_CTX);
  float s = 0.f;
#pragma unroll
  for (int base = 0; base < 16; base += 8) {
    float4 a[8], b[8];
#pragma unroll
    for (int j = 0; j < 8; ++j) a[j] = w4[lane + 64 * (base + j)];
#pragma unroll
    for (int j = 0; j < 8; ++j) b[j] = x4[lane + 64 * (base + j)];
#pragma unroll
    for (int j = 0; j < 8; ++j) s += dot4(a[j], b[j]);
  }
  s = wave_reduce_sum(s);
  if (lane == 0) out[r] = s;
}

extern "C" void kernel_launch(void* const* d_in, const int* in_sizes, int n_in,
                              void* d_out, int out_size, void* d_ws,
                              size_t ws_size, hipStream_t stream) {
  const float* hidden = (const float*)d_in[0];
  const float* k_cache = (const float*)d_in[1];
  const float* v_cache = (const float*)d_in[2];
  const float* Wq = (const float*)d_in[3];
  const float* Wk = (const float*)d_in[4];
  const float* Wv = (const float*)d_in[5];
  const float* Wo = (const float*)d_in[6];
  const int* pos = (const int*)d_in[7];
  float* out = (float*)d_out;
  float* ws = (float*)d_ws;

  qkv_rope_kernel<<<(HDIM + 2 * KVDIM) / 4, 256, 0, stream>>>(Wq, Wk, Wv,
                                                              hidden, pos, ws);
  attn_chunk_kernel<<<NKV * NCHUNK, 256, 0, stream>>>(k_cache, v_cache, ws);
  combine_kernel<<<NH, 256, 0, stream>>>(ws);
  out_matvec_kernel<<<HDIM / 4, 256, 0, stream>>>(Wo, ws, out);
}